// Round 2
// baseline (271.306 us; speedup 1.0000x reference)
//
#include <hip/hip_runtime.h>
#include <stdint.h>

typedef short short8 __attribute__((ext_vector_type(8)));
typedef float float4v __attribute__((ext_vector_type(4)));
typedef unsigned long long ull;

// Sizes fixed: N=8, M=512, D=64, B=8192. Block: one n, 128 b-rows, 8 waves,
// wave = 16 rows x 512 m. LDS = 80 KB exactly -> 2 blocks/CU; regs <= 128.
//
// LDS map:
//   [0, 65536)          E bf16 [512 m][128 B], XOR-swizzled rows (byte ^= (m&7)<<4)
//   [65536, 81920)      region2, time-multiplexed:
//     stage:   X bf16 [128 r][128 B] swizzled
//     phase A: esq f32 [512]            @ +0
//     phase B: samp chunks 8 x 1 KB     @ +8192   ([32 m][16 r] bf16)
//     finale:  avg f32 [4][512]         @ +0   (after bar4)
//              kl  f32 [8]              @ +8192 (after bar4)
#define R2      65536
#define LDS_SZ  81920

__device__ __forceinline__ unsigned cvtpk(float a, float b){
  unsigned d;
  asm("v_cvt_pk_bf16_f32 %0, %1, %2" : "=v"(d) : "v"(a), "v"(b));
  return d;
}
__device__ __forceinline__ float bfLO(unsigned r){ return __uint_as_float(r << 16); }
__device__ __forceinline__ float bfHI(unsigned r){ return __uint_as_float(r & 0xffff0000u); }

template<int OFF>
__device__ __forceinline__ ull tr16(unsigned a){
  ull d;
  asm volatile("ds_read_b64_tr_b16 %0, %1 offset:%c2" : "=v"(d) : "v"(a), "i"(OFF));
  return d;
}
__device__ __forceinline__ short8 mk8(ull lo, ull hi){
  union { ull q[2]; short8 v; } u; u.q[0] = lo; u.q[1] = hi; return u.v;
}

extern "C" __global__ void __launch_bounds__(512, 4)
vq_main(const float* __restrict__ gx, const float* __restrict__ ge,
        const float* __restrict__ gu, const float* __restrict__ gtau,
        float* __restrict__ gq, float* __restrict__ glg,
        float* __restrict__ ws_avg, float* __restrict__ ws_kl)
{
  extern __shared__ char smem[];
  const int tid = threadIdx.x;
  const int n   = blockIdx.x >> 6;
  const int b0  = (blockIdx.x & 63) * 128;

  // ---- stage embedding -> bf16 LDS (swizzled); esq kept in a register ----
  float esq_reg = 0.f;
  {
    const int m = tid;
    const float* src = ge + (size_t)(n * 512 + m) * 64;
    char* dst = smem + m * 128;
    const unsigned sw = (unsigned)((m & 7) << 4);
#pragma unroll
    for (int c = 0; c < 8; ++c) {
      float4 a = *(const float4*)(src + c * 8);
      float4 b = *(const float4*)(src + c * 8 + 4);
      esq_reg += a.x*a.x + a.y*a.y + a.z*a.z + a.w*a.w
               + b.x*b.x + b.y*b.y + b.z*b.z + b.w*b.w;
      uint4 v = { cvtpk(a.x, a.y), cvtpk(a.z, a.w), cvtpk(b.x, b.y), cvtpk(b.z, b.w) };
      *(uint4*)(dst + (((unsigned)(c * 16)) ^ sw)) = v;
    }
  }
  // ---- stage x tile -> bf16 LDS rows (swizzled) in region2 ----
  {
    const int r = tid >> 2, qq = tid & 3;
    const float* src = gx + (size_t)(b0 + r) * 512 + n * 64 + qq * 16;
    char* dst = smem + R2 + r * 128;
    const unsigned sw = (unsigned)((r & 7) << 4);
#pragma unroll
    for (int h = 0; h < 2; ++h) {
      float4 a = *(const float4*)(src + h * 8);
      float4 b = *(const float4*)(src + h * 8 + 4);
      uint4 v = { cvtpk(a.x, a.y), cvtpk(a.z, a.w), cvtpk(b.x, b.y), cvtpk(b.z, b.w) };
      *(uint4*)(dst + (((unsigned)((qq * 2 + h) * 16)) ^ sw)) = v;
    }
  }
  __syncthreads();                                    // bar1

  const int lane = tid & 63;
  const int w    = tid >> 6;
  const int l15  = lane & 15;
  const int kg   = lane >> 4;
  const unsigned swl = (unsigned)((l15 & 7) << 4);

  // ---- A-fragments for this wave's 16 rows ----
  const char* xrow = smem + R2 + (w * 16 + l15) * 128;
  const short8 a0 = *(const short8*)(xrow + (((unsigned)(kg * 16)) ^ swl));
  const short8 a1 = *(const short8*)(xrow + (((unsigned)(64 + kg * 16)) ^ swl));
  __syncthreads();                                    // bar2: X region free
  ((float*)(smem + R2))[tid] = esq_reg;               // esq[512] @ R2
  __syncthreads();                                    // bar3: esq visible

  const char* erow = smem + l15 * 128;
  const unsigned eo0 = ((unsigned)(kg * 16)) ^ swl;
  const unsigned eo1 = ((unsigned)(64 + kg * 16)) ^ swl;
  const float* esqp = (const float*)(smem + R2);

  // ---- phase A streamed: per-tile MFMA -> s -> pack bf16; online Z ----
  unsigned sy[64];
  float Z0 = 0.f, Z1 = 0.f, Z2r = 0.f, Z3 = 0.f;
#pragma unroll
  for (int t = 0; t < 32; ++t) {
    short8 bb0 = *(const short8*)(erow + t * 2048 + eo0);
    short8 bb1 = *(const short8*)(erow + t * 2048 + eo1);
    float4v d = (float4v){0.f, 0.f, 0.f, 0.f};
    d = __builtin_amdgcn_mfma_f32_16x16x32_bf16(a0, bb0, d, 0, 0, 0);
    d = __builtin_amdgcn_mfma_f32_16x16x32_bf16(a1, bb1, d, 0, 0, 0);
    const float eq = esqp[t * 16 + l15];
    const float s0 = 2.f * d[0] - eq;
    const float s1 = 2.f * d[1] - eq;
    const float s2 = 2.f * d[2] - eq;
    const float s3 = 2.f * d[3] - eq;
    Z0 += __expf(s0); Z1 += __expf(s1); Z2r += __expf(s2); Z3 += __expf(s3);
    sy[2 * t]     = cvtpk(s0, s1);
    sy[2 * t + 1] = cvtpk(s2, s3);
  }
#pragma unroll
  for (int o = 1; o < 16; o <<= 1) {
    Z0 += __shfl_xor(Z0, o); Z1 += __shfl_xor(Z1, o);
    Z2r += __shfl_xor(Z2r, o); Z3 += __shfl_xor(Z3, o);
  }
  float lse[4] = { __logf(Z0), __logf(Z1), __logf(Z2r), __logf(Z3) };

  // ---- pass 2: lp -> glg, gumbel, KL, y -> pack; running m2 ----
  const float invtau = 1.0f / gtau[0];
  const float logM = 6.2383246250395075f;
  float* lpb = glg + (size_t)(b0 + w * 16 + kg * 4) * 4096 + n * 512 + l15;
  const float* upb = gu + (size_t)n * 4194304 + (size_t)(b0 + w * 16 + kg * 4) * 512 + l15;
  float m2[4] = {-3e38f, -3e38f, -3e38f, -3e38f};
  float klv = 0.f;
#pragma unroll
  for (int t = 0; t < 32; ++t) {
    const unsigned r0 = sy[2 * t], r1 = sy[2 * t + 1];
    float yv[4];
#pragma unroll
    for (int j = 0; j < 4; ++j) {
      const float s = (j == 0) ? bfLO(r0) : (j == 1) ? bfHI(r0)
                    : (j == 2) ? bfLO(r1) : bfHI(r1);
      const float lp = s - lse[j];
      __builtin_nontemporal_store(lp, lpb + j * 4096 + t * 16);
      const float uu = __builtin_nontemporal_load(upb + j * 512 + t * 16);
      const float g = -__logf(-__logf(uu));
      klv += __expf(lp) * (lp + logM);
      const float y = (lp + g) * invtau;
      m2[j] = fmaxf(m2[j], y);
      yv[j] = y;
    }
    sy[2 * t]     = cvtpk(yv[0], yv[1]);
    sy[2 * t + 1] = cvtpk(yv[2], yv[3]);
  }
#pragma unroll
  for (int j = 0; j < 4; ++j)
#pragma unroll
    for (int o = 1; o < 16; o <<= 1) m2[j] = fmaxf(m2[j], __shfl_xor(m2[j], o));

  // ---- pass 3: e3 = exp(y - m2); Z2; pack e3 ----
  float Zs[4] = {0.f, 0.f, 0.f, 0.f};
#pragma unroll
  for (int t = 0; t < 32; ++t) {
    const unsigned r0 = sy[2 * t], r1 = sy[2 * t + 1];
    const float e0 = __expf(bfLO(r0) - m2[0]);
    const float e1 = __expf(bfHI(r0) - m2[1]);
    const float e2 = __expf(bfLO(r1) - m2[2]);
    const float e3 = __expf(bfHI(r1) - m2[3]);
    Zs[0] += e0; Zs[1] += e1; Zs[2] += e2; Zs[3] += e3;
    sy[2 * t]     = cvtpk(e0, e1);
    sy[2 * t + 1] = cvtpk(e2, e3);
  }
#pragma unroll
  for (int j = 0; j < 4; ++j)
#pragma unroll
    for (int o = 1; o < 16; o <<= 1) Zs[j] += __shfl_xor(Zs[j], o);
  float r2[4];
#pragma unroll
  for (int j = 0; j < 4; ++j) r2[j] = 1.0f / Zs[j];

  // ---- phase B: normalize -> samp chunk (1 KB/wave) -> quantize MFMA ----
  char* sampb = smem + R2 + 8192 + w * 1024;
  const unsigned trA = (unsigned)(uintptr_t)sampb
                     + (unsigned)(kg * 128 + (l15 >> 2) * 32 + (l15 & 3) * 8);
  const int mrow = kg * 4 + (l15 >> 2);
  const unsigned ebase = (unsigned)(uintptr_t)smem + (unsigned)(mrow * 128);
  const unsigned msw = ((unsigned)(mrow & 7)) << 4;
  unsigned trB0 = ebase + ((unsigned)(  0 + (l15 & 3) * 8) ^ msw);
  unsigned trB1 = ebase + ((unsigned)( 32 + (l15 & 3) * 8) ^ msw);
  unsigned trB2 = ebase + ((unsigned)( 64 + (l15 & 3) * 8) ^ msw);
  unsigned trB3 = ebase + ((unsigned)( 96 + (l15 & 3) * 8) ^ msw);

  float4v qacc0 = (float4v){0.f,0.f,0.f,0.f};
  float4v qacc1 = (float4v){0.f,0.f,0.f,0.f};
  float4v qacc2 = (float4v){0.f,0.f,0.f,0.f};
  float4v qacc3 = (float4v){0.f,0.f,0.f,0.f};
  unsigned avp[16];

#pragma unroll
  for (int s16 = 0; s16 < 16; ++s16) {
    float av01[2];
#pragma unroll
    for (int th = 0; th < 2; ++th) {
      const int t = s16 * 2 + th;
      const unsigned r0 = sy[2 * t], r1 = sy[2 * t + 1];
      const float s0 = bfLO(r0) * r2[0];
      const float s1 = bfHI(r0) * r2[1];
      const float s2 = bfLO(r1) * r2[2];
      const float s3 = bfHI(r1) * r2[3];
      const unsigned p0 = cvtpk(s0, s1);
      const unsigned p1 = cvtpk(s2, s3);
      *(ull*)(sampb + (th * 16 + l15) * 32 + kg * 8) = (ull)p0 | ((ull)p1 << 32);
      float av = s0 + s1 + s2 + s3;
      av += __shfl_xor(av, 16);
      av += __shfl_xor(av, 32);
      av01[th] = av;
    }
    avp[s16] = cvtpk(av01[0], av01[1]);
    asm volatile("s_waitcnt lgkmcnt(0)" ::: "memory");
    __builtin_amdgcn_sched_barrier(0);
    ull alo = tr16<0>(trA),    ahi = tr16<512>(trA);
    ull b0l = tr16<0>(trB0),   b0h = tr16<2048>(trB0);
    ull b1l = tr16<0>(trB1),   b1h = tr16<2048>(trB1);
    ull b2l = tr16<0>(trB2),   b2h = tr16<2048>(trB2);
    ull b3l = tr16<0>(trB3),   b3h = tr16<2048>(trB3);
    asm volatile("s_waitcnt lgkmcnt(0)" ::: "memory");
    __builtin_amdgcn_sched_barrier(0);
    short8 aa = mk8(alo, ahi);
    qacc0 = __builtin_amdgcn_mfma_f32_16x16x32_bf16(aa, mk8(b0l, b0h), qacc0, 0, 0, 0);
    qacc1 = __builtin_amdgcn_mfma_f32_16x16x32_bf16(aa, mk8(b1l, b1h), qacc1, 0, 0, 0);
    qacc2 = __builtin_amdgcn_mfma_f32_16x16x32_bf16(aa, mk8(b2l, b2h), qacc2, 0, 0, 0);
    qacc3 = __builtin_amdgcn_mfma_f32_16x16x32_bf16(aa, mk8(b3l, b3h), qacc3, 0, 0, 0);
    trB0 += 4096; trB1 += 4096; trB2 += 4096; trB3 += 4096;
  }

  // ---- store quantized ----
  {
    const size_t qb = (size_t)(b0 + w * 16 + kg * 4) * 512 + n * 64 + l15;
#pragma unroll
    for (int j = 0; j < 4; ++j) {
      __builtin_nontemporal_store(qacc0[j], gq + qb + (size_t)j * 512 +  0);
      __builtin_nontemporal_store(qacc1[j], gq + qb + (size_t)j * 512 + 16);
      __builtin_nontemporal_store(qacc2[j], gq + qb + (size_t)j * 512 + 32);
      __builtin_nontemporal_store(qacc3[j], gq + qb + (size_t)j * 512 + 48);
    }
  }

  // ---- KL wave-reduce (write after bar4) ----
#pragma unroll
  for (int o = 1; o < 64; o <<= 1) klv += __shfl_xor(klv, o);

  __syncthreads();                                    // bar4: esq+samp dead
  float* avgl = (float*)(smem + R2);                  // [4][512]
  float* kls  = (float*)(smem + R2 + 8192);
  if (lane == 0) kls[w] = klv;
  if (w < 4) {
#pragma unroll
    for (int s16 = 0; s16 < 16; ++s16) {
      if (kg == 0) {
        avgl[w * 512 + (s16 * 2 + 0) * 16 + l15] = bfLO(avp[s16]);
        avgl[w * 512 + (s16 * 2 + 1) * 16 + l15] = bfHI(avp[s16]);
      }
    }
  }
  __syncthreads();                                    // bar5
  if (w >= 4) {
#pragma unroll
    for (int s16 = 0; s16 < 16; ++s16) {
      if (kg == 0) {
        const int i0 = (w - 4) * 512 + (s16 * 2 + 0) * 16 + l15;
        const int i1 = (w - 4) * 512 + (s16 * 2 + 1) * 16 + l15;
        avgl[i0] += bfLO(avp[s16]);
        avgl[i1] += bfHI(avp[s16]);
      }
    }
  }
  __syncthreads();                                    // bar6
  {
    float s = avgl[tid] + avgl[512 + tid] + avgl[1024 + tid] + avgl[1536 + tid];
    ws_avg[(size_t)blockIdx.x * 512 + tid] = s;
    if (tid == 0) {
      float k = 0.f;
#pragma unroll
      for (int i = 0; i < 8; ++i) k += kls[i];
      ws_kl[blockIdx.x] = k;
    }
  }
}

extern "C" __global__ void __launch_bounds__(512)
vq_fin(const float* __restrict__ ws_avg, const float* __restrict__ ws_kl,
       float* __restrict__ scal)
{
  __shared__ float red[8];
  const int tid = threadIdx.x, lane = tid & 63, w = tid >> 6;
  float pps = 0.f;
  for (int n = 0; n < 8; ++n) {
    float s = 0.f;
    for (int bt = 0; bt < 64; ++bt) s += ws_avg[(size_t)(n * 64 + bt) * 512 + tid];
    const float avg = s * (1.0f / 8192.0f);
    float term = avg * __logf(avg + 1e-10f);
#pragma unroll
    for (int o = 1; o < 64; o <<= 1) term += __shfl_xor(term, o);
    __syncthreads();
    if (lane == 0) red[w] = term;
    __syncthreads();
    if (tid == 0) {
      float tt = 0.f;
#pragma unroll
      for (int i = 0; i < 8; ++i) tt += red[i];
      pps += __expf(-tt);
    }
  }
  float kv = ws_kl[tid];
#pragma unroll
  for (int o = 1; o < 64; o <<= 1) kv += __shfl_xor(kv, o);
  __syncthreads();
  if (lane == 0) red[w] = kv;
  __syncthreads();
  if (tid == 0) {
    float k = 0.f;
#pragma unroll
    for (int i = 0; i < 8; ++i) k += red[i];
    scal[0] = k * (1.0f / 8192.0f);
    scal[1] = pps;
  }
}

extern "C" void kernel_launch(void* const* d_in, const int* in_sizes, int n_in,
                              void* d_out, int out_size, void* d_ws, size_t ws_size,
                              hipStream_t stream)
{
  const float* gx = (const float*)d_in[0];
  const float* ge = (const float*)d_in[1];
  const float* gu = (const float*)d_in[2];
  const float* gt = (const float*)d_in[3];
  float* out  = (float*)d_out;
  float* gq   = out;
  float* scal = out + 4194304;
  float* glg  = out + 4194306;
  float* ws_avg = (float*)d_ws;
  float* ws_kl  = ws_avg + 512 * 512;

  hipFuncSetAttribute((const void*)vq_main,
                      hipFuncAttributeMaxDynamicSharedMemorySize, LDS_SZ);
  vq_main<<<dim3(512), dim3(512), LDS_SZ, stream>>>(gx, ge, gu, gt, gq, glg, ws_avg, ws_kl);
  vq_fin<<<dim3(1), dim3(512), 0, stream>>>(ws_avg, ws_kl, scal);
}

// Round 4
// 212.384 us; speedup vs baseline: 1.2774x; 1.2774x over previous
//
#include <hip/hip_runtime.h>
#include <stdint.h>

typedef short short8 __attribute__((ext_vector_type(8)));
typedef float float4v __attribute__((ext_vector_type(4)));
typedef unsigned long long ull;

// Sizes fixed: N=8, M=512, D=64, B=8192. Block: one n, 128 b-rows, 8 waves.
// Mapping: phase A computes mfma(E, X): D rows = m-local (kg*4+j),
// cols = b (l15). Lane owns 4 consecutive m for ONE b-row -> dwordx4 global IO.
//
// LDS map (80 KB -> 2 blocks/CU):
//   [0, 65536)      E bf16 [512 m][128 B], XOR-swizzled rows (byte ^= (m&7)<<4)
//   [65536, 81920)  region2, time-multiplexed:
//     stage:   X bf16 [128 r][128 B] swizzled
//     phase A: esq f32 [512]          @ +0
//     phase B: samp chunks 8 x 1 KB   @ +8192  ([32 m][16 r] bf16, 32B rows)
//     finale:  avg f32 [8][512]       @ +0     (after bar4; kls in dead E region)
#define R2      65536
#define LDS_SZ  81920

__device__ __forceinline__ unsigned cvtpk(float a, float b){
  unsigned d;
  asm("v_cvt_pk_bf16_f32 %0, %1, %2" : "=v"(d) : "v"(a), "v"(b));
  return d;
}
__device__ __forceinline__ unsigned short f2bf(float f){
  unsigned u = __float_as_uint(f);
  return (unsigned short)((u + 0x7FFFu + ((u >> 16) & 1u)) >> 16);
}
__device__ __forceinline__ float bfLO(unsigned r){ return __uint_as_float(r << 16); }
__device__ __forceinline__ float bfHI(unsigned r){ return __uint_as_float(r & 0xffff0000u); }

template<int OFF>
__device__ __forceinline__ ull tr16(unsigned a){
  ull d;
  asm volatile("ds_read_b64_tr_b16 %0, %1 offset:%c2" : "=v"(d) : "v"(a), "i"(OFF));
  return d;
}
__device__ __forceinline__ short8 mk8(ull lo, ull hi){
  union { ull q[2]; short8 v; } u; u.q[0] = lo; u.q[1] = hi; return u.v;
}

extern "C" __global__ void __launch_bounds__(512, 4)
vq_main(const float* __restrict__ gx, const float* __restrict__ ge,
        const float* __restrict__ gu, const float* __restrict__ gtau,
        float* __restrict__ gq, float* __restrict__ glg,
        float* __restrict__ ws_avg, float* __restrict__ ws_kl)
{
  extern __shared__ char smem[];
  const int tid = threadIdx.x;
  const int n   = blockIdx.x >> 6;
  const int b0  = (blockIdx.x & 63) * 128;

  // ---- stage embedding -> bf16 LDS (swizzled); esq kept in a register ----
  float esq_reg = 0.f;
  {
    const int m = tid;
    const float* src = ge + (size_t)(n * 512 + m) * 64;
    char* dst = smem + m * 128;
    const unsigned sw = (unsigned)((m & 7) << 4);
#pragma unroll
    for (int c = 0; c < 8; ++c) {
      float4 a = *(const float4*)(src + c * 8);
      float4 b = *(const float4*)(src + c * 8 + 4);
      esq_reg += a.x*a.x + a.y*a.y + a.z*a.z + a.w*a.w
               + b.x*b.x + b.y*b.y + b.z*b.z + b.w*b.w;
      uint4 v = { cvtpk(a.x, a.y), cvtpk(a.z, a.w), cvtpk(b.x, b.y), cvtpk(b.z, b.w) };
      *(uint4*)(dst + (((unsigned)(c * 16)) ^ sw)) = v;
    }
  }
  // ---- stage x tile -> bf16 LDS rows (swizzled) in region2 ----
  {
    const int r = tid >> 2, qq = tid & 3;
    const float* src = gx + (size_t)(b0 + r) * 512 + n * 64 + qq * 16;
    char* dst = smem + R2 + r * 128;
    const unsigned sw = (unsigned)((r & 7) << 4);
#pragma unroll
    for (int h = 0; h < 2; ++h) {
      float4 a = *(const float4*)(src + h * 8);
      float4 b = *(const float4*)(src + h * 8 + 4);
      uint4 v = { cvtpk(a.x, a.y), cvtpk(a.z, a.w), cvtpk(b.x, b.y), cvtpk(b.z, b.w) };
      *(uint4*)(dst + (((unsigned)((qq * 2 + h) * 16)) ^ sw)) = v;
    }
  }
  __syncthreads();                                    // bar1

  const int lane = tid & 63;
  const int w    = tid >> 6;
  const int l15  = lane & 15;
  const int kg   = lane >> 4;
  const unsigned swl = (unsigned)((l15 & 7) << 4);

  // ---- X B-fragments (col = b-row = w*16+l15) ----
  const char* xrow = smem + R2 + (w * 16 + l15) * 128;
  const short8 xb0 = *(const short8*)(xrow + (((unsigned)(kg * 16)) ^ swl));
  const short8 xb1 = *(const short8*)(xrow + (((unsigned)(64 + kg * 16)) ^ swl));
  __syncthreads();                                    // bar2: X region free
  ((float*)(smem + R2))[tid] = esq_reg;               // esq[512] @ R2
  __syncthreads();                                    // bar3

  const char* erow = smem + l15 * 128;
  const unsigned eo0 = ((unsigned)(kg * 16)) ^ swl;
  const unsigned eo1 = ((unsigned)(64 + kg * 16)) ^ swl;
  const float* esqp = (const float*)(smem + R2);

  // ---- phase A: per-tile mfma(E, X); s = 2*dot - esq; online Z, W=sum(es*s) ----
  unsigned sy[64];
  float Z = 0.f, Wk = 0.f;
#pragma unroll
  for (int t = 0; t < 32; ++t) {
    short8 eb0 = *(const short8*)(erow + t * 2048 + eo0);
    short8 eb1 = *(const short8*)(erow + t * 2048 + eo1);
    float4v d = (float4v){0.f, 0.f, 0.f, 0.f};
    d = __builtin_amdgcn_mfma_f32_16x16x32_bf16(eb0, xb0, d, 0, 0, 0);
    d = __builtin_amdgcn_mfma_f32_16x16x32_bf16(eb1, xb1, d, 0, 0, 0);
    const float4 eq = *(const float4*)(esqp + t * 16 + kg * 4);
    const float s0 = 2.f * d[0] - eq.x;
    const float s1 = 2.f * d[1] - eq.y;
    const float s2 = 2.f * d[2] - eq.z;
    const float s3 = 2.f * d[3] - eq.w;
    const float e0 = __expf(s0), e1 = __expf(s1), e2 = __expf(s2), e3 = __expf(s3);
    Z  += e0 + e1 + e2 + e3;
    Wk += e0 * s0 + e1 * s1 + e2 * s2 + e3 * s3;
    sy[2 * t]     = cvtpk(s0, s1);
    sy[2 * t + 1] = cvtpk(s2, s3);
  }
  // row stats: reduce across kg groups only (rows = b = l15)
  Z  += __shfl_xor(Z, 16);  Z  += __shfl_xor(Z, 32);
  Wk += __shfl_xor(Wk, 16); Wk += __shfl_xor(Wk, 32);
  const float lse = __logf(Z);
  const float logM = 6.2383246250395075f;
  float klrow = Wk / Z - lse + logM;                  // row KL (dup x4 over kg)

  // ---- pass 2: lp -> glg (x4), u (x4), gumbel, e3 = exp((lp+g)/tau) ----
  const float invtau = 1.0f / gtau[0];
  const float4* up4 = (const float4*)(gu + (size_t)n * 4194304
                     + (size_t)(b0 + w * 16 + l15) * 512 + kg * 4);
  float4v* lp4 = (float4v*)(glg + (size_t)(b0 + w * 16 + l15) * 4096 + n * 512 + kg * 4);
  float Z2 = 0.f;
  {
    float4 u0 = up4[0], u1 = up4[4], u2 = up4[8], u3 = up4[12];
#pragma unroll
    for (int g = 0; g < 8; ++g) {
      float4 v0, v1, v2, v3;
      if (g < 7) {
        v0 = up4[(g + 1) * 16];      v1 = up4[(g + 1) * 16 + 4];
        v2 = up4[(g + 1) * 16 + 8];  v3 = up4[(g + 1) * 16 + 12];
      }
#pragma unroll
      for (int q = 0; q < 4; ++q) {
        const int t = g * 4 + q;
        const float4 uu = (q == 0) ? u0 : (q == 1) ? u1 : (q == 2) ? u2 : u3;
        const unsigned r0 = sy[2 * t], r1 = sy[2 * t + 1];
        const float lp0 = bfLO(r0) - lse, lp1 = bfHI(r0) - lse;
        const float lp2 = bfLO(r1) - lse, lp3 = bfHI(r1) - lse;
        float4v lpv = { lp0, lp1, lp2, lp3 };
        __builtin_nontemporal_store(lpv, lp4 + t * 4);
        const float g0 = -__logf(-__logf(uu.x));
        const float g1 = -__logf(-__logf(uu.y));
        const float g2 = -__logf(-__logf(uu.z));
        const float g3 = -__logf(-__logf(uu.w));
        const float y0 = __expf((lp0 + g0) * invtau);
        const float y1 = __expf((lp1 + g1) * invtau);
        const float y2 = __expf((lp2 + g2) * invtau);
        const float y3 = __expf((lp3 + g3) * invtau);
        Z2 += y0 + y1 + y2 + y3;
        sy[2 * t]     = cvtpk(y0, y1);
        sy[2 * t + 1] = cvtpk(y2, y3);
      }
      u0 = v0; u1 = v1; u2 = v2; u3 = v3;
    }
  }
  Z2 += __shfl_xor(Z2, 16); Z2 += __shfl_xor(Z2, 32);
  const float rz2 = 1.0f / Z2;

  // ---- phase B: samples -> samp chunk; quantize MFMA + avg-MFMA ----
  ushort* sampw = (ushort*)(smem + R2 + 8192 + w * 1024);   // [32 m][16 r]
  const char* sampc = (const char*)sampw;
  const unsigned trA = (unsigned)(uintptr_t)sampw
                     + (unsigned)(kg * 128 + (l15 >> 2) * 32 + (l15 & 3) * 8);
  const int mrow = kg * 4 + (l15 >> 2);
  const unsigned ebase = (unsigned)(uintptr_t)smem + (unsigned)(mrow * 128);
  const unsigned msw = ((unsigned)(mrow & 7)) << 4;
  unsigned trB0 = ebase + ((unsigned)(  0 + (l15 & 3) * 8) ^ msw);
  unsigned trB1 = ebase + ((unsigned)( 32 + (l15 & 3) * 8) ^ msw);
  unsigned trB2 = ebase + ((unsigned)( 64 + (l15 & 3) * 8) ^ msw);
  unsigned trB3 = ebase + ((unsigned)( 96 + (l15 & 3) * 8) ^ msw);

  float4v qacc0 = (float4v){0.f,0.f,0.f,0.f};
  float4v qacc1 = (float4v){0.f,0.f,0.f,0.f};
  float4v qacc2 = (float4v){0.f,0.f,0.f,0.f};
  float4v qacc3 = (float4v){0.f,0.f,0.f,0.f};
  float4v avgA  = (float4v){0.f,0.f,0.f,0.f};
  float4v avgB  = (float4v){0.f,0.f,0.f,0.f};

#pragma unroll
  for (int c = 0; c < 16; ++c) {
#pragma unroll
    for (int th = 0; th < 2; ++th) {
      const int t = c * 2 + th;
      const unsigned r0 = sy[2 * t], r1 = sy[2 * t + 1];
      const float s0 = bfLO(r0) * rz2, s1 = bfHI(r0) * rz2;
      const float s2 = bfLO(r1) * rz2, s3 = bfHI(r1) * rz2;
      sampw[(th * 16 + kg * 4 + 0) * 16 + l15] = f2bf(s0);
      sampw[(th * 16 + kg * 4 + 1) * 16 + l15] = f2bf(s1);
      sampw[(th * 16 + kg * 4 + 2) * 16 + l15] = f2bf(s2);
      sampw[(th * 16 + kg * 4 + 3) * 16 + l15] = f2bf(s3);
    }
    asm volatile("s_waitcnt lgkmcnt(0)" ::: "memory");
    __builtin_amdgcn_sched_barrier(0);
    // avg A-frags: natural row-major reads of samp (kg>=2 dup kg&1; zeroed by bsel)
    const short8 avA = *(const short8*)(sampc + l15 * 32 + (kg & 1) * 16);
    const short8 avB = *(const short8*)(sampc + 512 + l15 * 32 + (kg & 1) * 16);
    ull alo = tr16<0>(trA),  ahi = tr16<512>(trA);
    ull b0l = tr16<0>(trB0), b0h = tr16<2048>(trB0);
    ull b1l = tr16<0>(trB1), b1h = tr16<2048>(trB1);
    ull b2l = tr16<0>(trB2), b2h = tr16<2048>(trB2);
    ull b3l = tr16<0>(trB3), b3h = tr16<2048>(trB3);
    asm volatile("s_waitcnt lgkmcnt(0)" ::: "memory");
    __builtin_amdgcn_sched_barrier(0);
    const unsigned onv = ((l15 == c) && (kg < 2)) ? 0x3F803F80u : 0u;
    union { unsigned u[4]; short8 v; } bs;
    bs.u[0] = onv; bs.u[1] = onv; bs.u[2] = onv; bs.u[3] = onv;
    short8 aa = mk8(alo, ahi);
    qacc0 = __builtin_amdgcn_mfma_f32_16x16x32_bf16(aa, mk8(b0l, b0h), qacc0, 0, 0, 0);
    qacc1 = __builtin_amdgcn_mfma_f32_16x16x32_bf16(aa, mk8(b1l, b1h), qacc1, 0, 0, 0);
    qacc2 = __builtin_amdgcn_mfma_f32_16x16x32_bf16(aa, mk8(b2l, b2h), qacc2, 0, 0, 0);
    qacc3 = __builtin_amdgcn_mfma_f32_16x16x32_bf16(aa, mk8(b3l, b3h), qacc3, 0, 0, 0);
    avgA  = __builtin_amdgcn_mfma_f32_16x16x32_bf16(avA, bs.v, avgA, 0, 0, 0);
    avgB  = __builtin_amdgcn_mfma_f32_16x16x32_bf16(avB, bs.v, avgB, 0, 0, 0);
    trB0 += 4096; trB1 += 4096; trB2 += 4096; trB3 += 4096;
  }

  // ---- store quantized (old C-layout: row b = kg*4+j, col d = l15) ----
  {
    const size_t qb = (size_t)(b0 + w * 16 + kg * 4) * 512 + n * 64 + l15;
#pragma unroll
    for (int j = 0; j < 4; ++j) {
      gq[qb + (size_t)j * 512 +  0] = qacc0[j];
      gq[qb + (size_t)j * 512 + 16] = qacc1[j];
      gq[qb + (size_t)j * 512 + 32] = qacc2[j];
      gq[qb + (size_t)j * 512 + 48] = qacc3[j];
    }
  }

  // ---- KL full-wave value (rows = l15; dup over kg collapses, not sums) ----
  klrow += __shfl_xor(klrow, 1); klrow += __shfl_xor(klrow, 2);
  klrow += __shfl_xor(klrow, 4); klrow += __shfl_xor(klrow, 8);

  __syncthreads();                                    // bar4: samp + esq + E dead
  float* avgl = (float*)(smem + R2);                  // [8][512]
  float* kls  = (float*)smem;                         // in dead E region
  if (lane == 0) kls[w] = klrow;
  // avgA[j]: m = l15*32 + kg*4 + j ; avgB[j]: m = l15*32 + 16 + kg*4 + j
  *(float4v*)(avgl + w * 512 + l15 * 32 + kg * 4)      = avgA;
  *(float4v*)(avgl + w * 512 + l15 * 32 + 16 + kg * 4) = avgB;
  __syncthreads();                                    // bar5
  {
    float s = 0.f;
#pragma unroll
    for (int ww = 0; ww < 8; ++ww) s += avgl[ww * 512 + tid];
    ws_avg[(size_t)blockIdx.x * 512 + tid] = s;
    if (tid == 0) {
      float k = 0.f;
#pragma unroll
      for (int i = 0; i < 8; ++i) k += kls[i];
      ws_kl[blockIdx.x] = k;
    }
  }
}

extern "C" __global__ void __launch_bounds__(512)
vq_fin(const float* __restrict__ ws_avg, const float* __restrict__ ws_kl,
       float* __restrict__ scal)
{
  __shared__ float red[8];
  const int tid = threadIdx.x, lane = tid & 63, w = tid >> 6;
  float pps = 0.f;
  for (int n = 0; n < 8; ++n) {
    float s = 0.f;
    for (int bt = 0; bt < 64; ++bt) s += ws_avg[(size_t)(n * 64 + bt) * 512 + tid];
    const float avg = s * (1.0f / 8192.0f);
    float term = avg * __logf(avg + 1e-10f);
#pragma unroll
    for (int o = 1; o < 64; o <<= 1) term += __shfl_xor(term, o);
    __syncthreads();
    if (lane == 0) red[w] = term;
    __syncthreads();
    if (tid == 0) {
      float tt = 0.f;
#pragma unroll
      for (int i = 0; i < 8; ++i) tt += red[i];
      pps += __expf(-tt);
    }
  }
  float kv = ws_kl[tid];
#pragma unroll
  for (int o = 1; o < 64; o <<= 1) kv += __shfl_xor(kv, o);
  __syncthreads();
  if (lane == 0) red[w] = kv;
  __syncthreads();
  if (tid == 0) {
    float k = 0.f;
#pragma unroll
    for (int i = 0; i < 8; ++i) k += red[i];
    scal[0] = k * (1.0f / 8192.0f);
    scal[1] = pps;
  }
}

extern "C" void kernel_launch(void* const* d_in, const int* in_sizes, int n_in,
                              void* d_out, int out_size, void* d_ws, size_t ws_size,
                              hipStream_t stream)
{
  const float* gx = (const float*)d_in[0];
  const float* ge = (const float*)d_in[1];
  const float* gu = (const float*)d_in[2];
  const float* gt = (const float*)d_in[3];
  float* out  = (float*)d_out;
  float* gq   = out;
  float* scal = out + 4194304;
  float* glg  = out + 4194306;
  float* ws_avg = (float*)d_ws;
  float* ws_kl  = ws_avg + 512 * 512;

  (void)hipFuncSetAttribute((const void*)vq_main,
                            hipFuncAttributeMaxDynamicSharedMemorySize, LDS_SZ);
  vq_main<<<dim3(512), dim3(512), LDS_SZ, stream>>>(gx, ge, gu, gt, gq, glg, ws_avg, ws_kl);
  vq_fin<<<dim3(1), dim3(512), 0, stream>>>(ws_avg, ws_kl, scal);
}

// Round 6
// 125.833 us; speedup vs baseline: 2.1561x; 1.6878x over previous
//
#include <hip/hip_runtime.h>
#include <stdint.h>

typedef short short8 __attribute__((ext_vector_type(8)));
typedef float float4v __attribute__((ext_vector_type(4)));
typedef unsigned long long ull;

// Sizes fixed: N=8, M=512, D=64, B=8192. Block: one n, 128 b-rows, 8 waves.
// mfma(E, X): C rows = m-local (kg*4+j), cols = b (l15).
// Sweep 1 streams u and computes Z (softmax-1), Wk (KL identity) AND
// Z2' = sum(exp((s+g)/tau)) via shift-invariance (no lse needed).
// Sweep 2 recomputes s and g, stores lp, normalizes y*rz2 BEFORE the LDS
// store, then quantize/avg MFMAs consume correctly-normalized samples.
//
// LDS map (80 KB -> 2 blocks/CU):
//   [0, 65536)      E bf16 [512 m][128 B], XOR-swizzled rows (byte ^= (m&7)<<4)
//   [65536, 81920)  region2, time-multiplexed:
//     stage:   X bf16 [128 r][128 B] swizzled
//     sweeps:  esq f32 [512]          @ +0
//     sweep2:  samp chunks 8 x 1 KB   @ +8192  ([32 m][16 r] bf16, 32B rows)
//     finale:  avg f32 [8][512]       @ +0     (after bar4; kls in dead E region)
#define R2      65536
#define LDS_SZ  81920

__device__ __forceinline__ unsigned cvtpk(float a, float b){
  unsigned d;
  asm("v_cvt_pk_bf16_f32 %0, %1, %2" : "=v"(d) : "v"(a), "v"(b));
  return d;
}
__device__ __forceinline__ unsigned short f2bf(float f){
  unsigned u = __float_as_uint(f);
  return (unsigned short)((u + 0x7FFFu + ((u >> 16) & 1u)) >> 16);
}

template<int OFF>
__device__ __forceinline__ ull tr16(unsigned a){
  ull d;
  asm volatile("ds_read_b64_tr_b16 %0, %1 offset:%c2" : "=v"(d) : "v"(a), "i"(OFF));
  return d;
}
__device__ __forceinline__ short8 mk8(ull lo, ull hi){
  union { ull q[2]; short8 v; } u; u.q[0] = lo; u.q[1] = hi; return u.v;
}

extern "C" __global__ void __launch_bounds__(512, 4)
vq_main(const float* __restrict__ gx, const float* __restrict__ ge,
        const float* __restrict__ gu, const float* __restrict__ gtau,
        float* __restrict__ gq, float* __restrict__ glg,
        float* __restrict__ ws_avg, float* __restrict__ ws_kl)
{
  extern __shared__ char smem[];
  const int tid = threadIdx.x;
  const int n   = blockIdx.x >> 6;
  const int b0  = (blockIdx.x & 63) * 128;

  // ---- stage embedding -> bf16 LDS (swizzled); esq kept in a register ----
  float esq_reg = 0.f;
  {
    const int m = tid;
    const float* src = ge + (size_t)(n * 512 + m) * 64;
    char* dst = smem + m * 128;
    const unsigned sw = (unsigned)((m & 7) << 4);
#pragma unroll
    for (int c = 0; c < 8; ++c) {
      float4 a = *(const float4*)(src + c * 8);
      float4 b = *(const float4*)(src + c * 8 + 4);
      esq_reg += a.x*a.x + a.y*a.y + a.z*a.z + a.w*a.w
               + b.x*b.x + b.y*b.y + b.z*b.z + b.w*b.w;
      uint4 v = { cvtpk(a.x, a.y), cvtpk(a.z, a.w), cvtpk(b.x, b.y), cvtpk(b.z, b.w) };
      *(uint4*)(dst + (((unsigned)(c * 16)) ^ sw)) = v;
    }
  }
  // ---- stage x tile -> bf16 LDS rows (swizzled) in region2 ----
  {
    const int r = tid >> 2, qq = tid & 3;
    const float* src = gx + (size_t)(b0 + r) * 512 + n * 64 + qq * 16;
    char* dst = smem + R2 + r * 128;
    const unsigned sw = (unsigned)((r & 7) << 4);
#pragma unroll
    for (int h = 0; h < 2; ++h) {
      float4 a = *(const float4*)(src + h * 8);
      float4 b = *(const float4*)(src + h * 8 + 4);
      uint4 v = { cvtpk(a.x, a.y), cvtpk(a.z, a.w), cvtpk(b.x, b.y), cvtpk(b.z, b.w) };
      *(uint4*)(dst + (((unsigned)((qq * 2 + h) * 16)) ^ sw)) = v;
    }
  }
  __syncthreads();                                    // bar1

  const int lane = tid & 63;
  const int w    = tid >> 6;
  const int l15  = lane & 15;
  const int kg   = lane >> 4;
  const unsigned swl = (unsigned)((l15 & 7) << 4);

  // ---- X B-fragments (col = b-row = w*16+l15) ----
  const char* xrow = smem + R2 + (w * 16 + l15) * 128;
  const short8 xb0 = *(const short8*)(xrow + (((unsigned)(kg * 16)) ^ swl));
  const short8 xb1 = *(const short8*)(xrow + (((unsigned)(64 + kg * 16)) ^ swl));
  __syncthreads();                                    // bar2: X region free
  ((float*)(smem + R2))[tid] = esq_reg;               // esq[512] @ R2
  __syncthreads();                                    // bar3

  const char* erow = smem + l15 * 128;
  const unsigned eo0 = ((unsigned)(kg * 16)) ^ swl;
  const unsigned eo1 = ((unsigned)(64 + kg * 16)) ^ swl;
  const float* esqp = (const float*)(smem + R2);

  const float invtau = 1.0f / gtau[0];
  const float4* up4 = (const float4*)(gu + (size_t)n * 4194304
                     + (size_t)(b0 + w * 16 + l15) * 512 + kg * 4);

  // ---- sweep 1: Z, Wk, and Z2' = sum(exp((s+g)/tau)) (lse-free shift) ----
  float Z = 0.f, Wk = 0.f, Z2 = 0.f;
  {
    float4 Pa = up4[0], Pb = up4[4], Pc = up4[8], Pd = up4[12];
#pragma unroll
    for (int t = 0; t < 32; ++t) {
      short8 eb0 = *(const short8*)(erow + t * 2048 + eo0);
      short8 eb1 = *(const short8*)(erow + t * 2048 + eo1);
      float4v d = (float4v){0.f, 0.f, 0.f, 0.f};
      d = __builtin_amdgcn_mfma_f32_16x16x32_bf16(eb0, xb0, d, 0, 0, 0);
      d = __builtin_amdgcn_mfma_f32_16x16x32_bf16(eb1, xb1, d, 0, 0, 0);
      const float4 eq = *(const float4*)(esqp + t * 16 + kg * 4);
      const float s0 = 2.f * d[0] - eq.x;
      const float s1 = 2.f * d[1] - eq.y;
      const float s2 = 2.f * d[2] - eq.z;
      const float s3 = 2.f * d[3] - eq.w;
      const float e0 = __expf(s0), e1 = __expf(s1), e2 = __expf(s2), e3 = __expf(s3);
      Z  += e0 + e1 + e2 + e3;
      Wk += e0 * s0 + e1 * s1 + e2 * s2 + e3 * s3;
      const float4 uu = Pa;
      Pa = Pb; Pb = Pc; Pc = Pd;
      if (t < 28) Pd = up4[(t + 4) * 4];
      const float g0 = -__logf(-__logf(uu.x));
      const float g1 = -__logf(-__logf(uu.y));
      const float g2 = -__logf(-__logf(uu.z));
      const float g3 = -__logf(-__logf(uu.w));
      Z2 += __expf((s0 + g0) * invtau) + __expf((s1 + g1) * invtau)
          + __expf((s2 + g2) * invtau) + __expf((s3 + g3) * invtau);
    }
  }
  Z  += __shfl_xor(Z, 16);  Z  += __shfl_xor(Z, 32);
  Wk += __shfl_xor(Wk, 16); Wk += __shfl_xor(Wk, 32);
  Z2 += __shfl_xor(Z2, 16); Z2 += __shfl_xor(Z2, 32);
  const float lse = __logf(Z);
  const float logM = 6.2383246250395075f;
  float klrow = Wk / Z - lse + logM;                  // row KL (dup x4 over kg)
  const float rz2 = 1.0f / Z2;

  // ---- sweep 2 fused with quantize: recompute s,g; lp -> glg; y*rz2 -> LDS ----
  float4v* lp4 = (float4v*)(glg + (size_t)(b0 + w * 16 + l15) * 4096 + n * 512 + kg * 4);
  ushort* sampw = (ushort*)(smem + R2 + 8192 + w * 1024);   // [32 m][16 r]
  const char* sampc = (const char*)sampw;
  const unsigned trA = (unsigned)(uintptr_t)sampw
                     + (unsigned)(kg * 128 + (l15 >> 2) * 32 + (l15 & 3) * 8);
  const int mrow = kg * 4 + (l15 >> 2);
  const unsigned ebase = (unsigned)(uintptr_t)smem + (unsigned)(mrow * 128);
  const unsigned msw = ((unsigned)(mrow & 7)) << 4;
  unsigned trB0 = ebase + ((unsigned)(  0 + (l15 & 3) * 8) ^ msw);
  unsigned trB1 = ebase + ((unsigned)( 32 + (l15 & 3) * 8) ^ msw);
  unsigned trB2 = ebase + ((unsigned)( 64 + (l15 & 3) * 8) ^ msw);
  unsigned trB3 = ebase + ((unsigned)( 96 + (l15 & 3) * 8) ^ msw);

  float4v qacc0 = (float4v){0.f,0.f,0.f,0.f};
  float4v qacc1 = (float4v){0.f,0.f,0.f,0.f};
  float4v qacc2 = (float4v){0.f,0.f,0.f,0.f};
  float4v qacc3 = (float4v){0.f,0.f,0.f,0.f};
  float4v avgA  = (float4v){0.f,0.f,0.f,0.f};
  float4v avgB  = (float4v){0.f,0.f,0.f,0.f};

  float4 P0 = up4[0], P1 = up4[4], P2 = up4[8], P3 = up4[12];
#pragma unroll
  for (int c = 0; c < 16; ++c) {
    const float4 cu0 = P0, cu1 = P1;
    P0 = P2; P1 = P3;
    if (c < 14) { P2 = up4[(2 * c + 4) * 4]; P3 = up4[(2 * c + 5) * 4]; }
#pragma unroll
    for (int th = 0; th < 2; ++th) {
      const int t = c * 2 + th;
      short8 eb0 = *(const short8*)(erow + t * 2048 + eo0);
      short8 eb1 = *(const short8*)(erow + t * 2048 + eo1);
      float4v d = (float4v){0.f, 0.f, 0.f, 0.f};
      d = __builtin_amdgcn_mfma_f32_16x16x32_bf16(eb0, xb0, d, 0, 0, 0);
      d = __builtin_amdgcn_mfma_f32_16x16x32_bf16(eb1, xb1, d, 0, 0, 0);
      const float4 eq = *(const float4*)(esqp + t * 16 + kg * 4);
      const float s0 = 2.f * d[0] - eq.x;
      const float s1 = 2.f * d[1] - eq.y;
      const float s2 = 2.f * d[2] - eq.z;
      const float s3 = 2.f * d[3] - eq.w;
      float4v lpv = { s0 - lse, s1 - lse, s2 - lse, s3 - lse };
      lp4[t * 4] = lpv;
      const float4 uu = (th == 0) ? cu0 : cu1;
      const float g0 = -__logf(-__logf(uu.x));
      const float g1 = -__logf(-__logf(uu.y));
      const float g2 = -__logf(-__logf(uu.z));
      const float g3 = -__logf(-__logf(uu.w));
      const float y0 = __expf((s0 + g0) * invtau) * rz2;
      const float y1 = __expf((s1 + g1) * invtau) * rz2;
      const float y2 = __expf((s2 + g2) * invtau) * rz2;
      const float y3 = __expf((s3 + g3) * invtau) * rz2;
      sampw[(th * 16 + kg * 4 + 0) * 16 + l15] = f2bf(y0);
      sampw[(th * 16 + kg * 4 + 1) * 16 + l15] = f2bf(y1);
      sampw[(th * 16 + kg * 4 + 2) * 16 + l15] = f2bf(y2);
      sampw[(th * 16 + kg * 4 + 3) * 16 + l15] = f2bf(y3);
    }
    asm volatile("s_waitcnt lgkmcnt(0)" ::: "memory");
    __builtin_amdgcn_sched_barrier(0);
    const short8 avA = *(const short8*)(sampc + l15 * 32 + (kg & 1) * 16);
    const short8 avB = *(const short8*)(sampc + 512 + l15 * 32 + (kg & 1) * 16);
    ull alo = tr16<0>(trA),  ahi = tr16<512>(trA);
    ull b0l = tr16<0>(trB0), b0h = tr16<2048>(trB0);
    ull b1l = tr16<0>(trB1), b1h = tr16<2048>(trB1);
    ull b2l = tr16<0>(trB2), b2h = tr16<2048>(trB2);
    ull b3l = tr16<0>(trB3), b3h = tr16<2048>(trB3);
    asm volatile("s_waitcnt lgkmcnt(0)" ::: "memory");
    __builtin_amdgcn_sched_barrier(0);
    const unsigned onv = ((l15 == c) && (kg < 2)) ? 0x3F803F80u : 0u;
    union { unsigned u[4]; short8 v; } bs;
    bs.u[0] = onv; bs.u[1] = onv; bs.u[2] = onv; bs.u[3] = onv;
    short8 aa = mk8(alo, ahi);
    qacc0 = __builtin_amdgcn_mfma_f32_16x16x32_bf16(aa, mk8(b0l, b0h), qacc0, 0, 0, 0);
    qacc1 = __builtin_amdgcn_mfma_f32_16x16x32_bf16(aa, mk8(b1l, b1h), qacc1, 0, 0, 0);
    qacc2 = __builtin_amdgcn_mfma_f32_16x16x32_bf16(aa, mk8(b2l, b2h), qacc2, 0, 0, 0);
    qacc3 = __builtin_amdgcn_mfma_f32_16x16x32_bf16(aa, mk8(b3l, b3h), qacc3, 0, 0, 0);
    avgA  = __builtin_amdgcn_mfma_f32_16x16x32_bf16(avA, bs.v, avgA, 0, 0, 0);
    avgB  = __builtin_amdgcn_mfma_f32_16x16x32_bf16(avB, bs.v, avgB, 0, 0, 0);
    trB0 += 4096; trB1 += 4096; trB2 += 4096; trB3 += 4096;
  }

  // ---- store quantized (row b = kg*4+j, col d = l15) ----
  {
    const size_t qb = (size_t)(b0 + w * 16 + kg * 4) * 512 + n * 64 + l15;
#pragma unroll
    for (int j = 0; j < 4; ++j) {
      gq[qb + (size_t)j * 512 +  0] = qacc0[j];
      gq[qb + (size_t)j * 512 + 16] = qacc1[j];
      gq[qb + (size_t)j * 512 + 32] = qacc2[j];
      gq[qb + (size_t)j * 512 + 48] = qacc3[j];
    }
  }

  // ---- KL full-wave value (rows = l15; dup over kg collapses, not sums) ----
  klrow += __shfl_xor(klrow, 1); klrow += __shfl_xor(klrow, 2);
  klrow += __shfl_xor(klrow, 4); klrow += __shfl_xor(klrow, 8);

  __syncthreads();                                    // bar4: samp + esq + E dead
  float* avgl = (float*)(smem + R2);                  // [8][512]
  float* kls  = (float*)smem;                         // in dead E region
  if (lane == 0) kls[w] = klrow;
  // avgA[j]: m = l15*32 + kg*4 + j ; avgB[j]: m = l15*32 + 16 + kg*4 + j
  *(float4v*)(avgl + w * 512 + l15 * 32 + kg * 4)      = avgA;
  *(float4v*)(avgl + w * 512 + l15 * 32 + 16 + kg * 4) = avgB;
  __syncthreads();                                    // bar5
  {
    float s = 0.f;
#pragma unroll
    for (int ww = 0; ww < 8; ++ww) s += avgl[ww * 512 + tid];
    ws_avg[(size_t)blockIdx.x * 512 + tid] = s;
    if (tid == 0) {
      float k = 0.f;
#pragma unroll
      for (int i = 0; i < 8; ++i) k += kls[i];
      ws_kl[blockIdx.x] = k;
    }
  }
}

extern "C" __global__ void __launch_bounds__(512)
vq_fin(const float* __restrict__ ws_avg, const float* __restrict__ ws_kl,
       float* __restrict__ scal)
{
  __shared__ float red[8];
  const int tid = threadIdx.x, lane = tid & 63, w = tid >> 6;
  float pps = 0.f;
  for (int n = 0; n < 8; ++n) {
    float s = 0.f;
    for (int bt = 0; bt < 64; ++bt) s += ws_avg[(size_t)(n * 64 + bt) * 512 + tid];
    const float avg = s * (1.0f / 8192.0f);
    float term = avg * __logf(avg + 1e-10f);
#pragma unroll
    for (int o = 1; o < 64; o <<= 1) term += __shfl_xor(term, o);
    __syncthreads();
    if (lane == 0) red[w] = term;
    __syncthreads();
    if (tid == 0) {
      float tt = 0.f;
#pragma unroll
      for (int i = 0; i < 8; ++i) tt += red[i];
      pps += __expf(-tt);
    }
  }
  float kv = ws_kl[tid];
#pragma unroll
  for (int o = 1; o < 64; o <<= 1) kv += __shfl_xor(kv, o);
  __syncthreads();
  if (lane == 0) red[w] = kv;
  __syncthreads();
  if (tid == 0) {
    float k = 0.f;
#pragma unroll
    for (int i = 0; i < 8; ++i) k += red[i];
    scal[0] = k * (1.0f / 8192.0f);
    scal[1] = pps;
  }
}

extern "C" void kernel_launch(void* const* d_in, const int* in_sizes, int n_in,
                              void* d_out, int out_size, void* d_ws, size_t ws_size,
                              hipStream_t stream)
{
  const float* gx = (const float*)d_in[0];
  const float* ge = (const float*)d_in[1];
  const float* gu = (const float*)d_in[2];
  const float* gt = (const float*)d_in[3];
  float* out  = (float*)d_out;
  float* gq   = out;
  float* scal = out + 4194304;
  float* glg  = out + 4194306;
  float* ws_avg = (float*)d_ws;
  float* ws_kl  = ws_avg + 512 * 512;

  (void)hipFuncSetAttribute((const void*)vq_main,
                            hipFuncAttributeMaxDynamicSharedMemorySize, LDS_SZ);
  vq_main<<<dim3(512), dim3(512), LDS_SZ, stream>>>(gx, ge, gu, gt, gq, glg, ws_avg, ws_kl);
  vq_fin<<<dim3(1), dim3(512), 0, stream>>>(ws_avg, ws_kl, scal);
}